// Round 15
// baseline (57865.747 us; speedup 1.0000x reference)
//
#include <hip/hip_runtime.h>
#include <cstddef>
#include <cstdint>

#define T_INN 200
#define T_OUTT 400
#define BB 64
#define DENC 512
#define NMEL 80

typedef unsigned short u16;
typedef unsigned long long u64;
typedef __bf16 bf16x8 __attribute__((ext_vector_type(8)));
typedef float f32x4 __attribute__((ext_vector_type(4)));

// fast sigmoid/tanh (validated R5-R14: absmax unchanged at 0.00098)
__device__ __forceinline__ float sigf(float x) {
  return __builtin_amdgcn_rcpf(1.0f + __expf(-x));
}
__device__ __forceinline__ float ftanh(float x) {
  float e2 = __expf(2.0f * x);
  return 1.0f - 2.0f * __builtin_amdgcn_rcpf(e2 + 1.0f);
}

// round-to-nearest-even f32 -> bf16
__device__ __forceinline__ u16 f2bf(float f) {
  unsigned u = __float_as_uint(f);
  unsigned r = u + 0x7fffu + ((u >> 16) & 1u);
  return (u16)(r >> 16);
}

__device__ __forceinline__ bf16x8 ldbf8(const u16* p) { return *(const bf16x8*)p; }

// ---- agent-scope (LLC-coherent) accessors for cross-block state ----------
// Compiler-tracked (waitcnt only before use; loads issue back-to-back).
// Correctness of this scheme verified in R4 (passed with identical absmax).
__device__ __forceinline__ bf16x8 ldbf8_cc(const u16* p) {
  union { u64 q[2]; bf16x8 v; } u;
  u.q[0] = __hip_atomic_load((const u64*)p,     __ATOMIC_RELAXED, __HIP_MEMORY_SCOPE_AGENT);
  u.q[1] = __hip_atomic_load((const u64*)p + 1, __ATOMIC_RELAXED, __HIP_MEMORY_SCOPE_AGENT);
  return u.v;
}
__device__ __forceinline__ float ldf_cc(const float* p) {
  return __hip_atomic_load(p, __ATOMIC_RELAXED, __HIP_MEMORY_SCOPE_AGENT);
}
__device__ __forceinline__ float4 ldf4_cc(const float* p) {
  union { u64 q[2]; float4 v; } u;
  u.q[0] = __hip_atomic_load((const u64*)p,     __ATOMIC_RELAXED, __HIP_MEMORY_SCOPE_AGENT);
  u.q[1] = __hip_atomic_load((const u64*)p + 1, __ATOMIC_RELAXED, __HIP_MEMORY_SCOPE_AGENT);
  return u.v;
}
__device__ __forceinline__ void stf_cc(float* p, float v) {
  __hip_atomic_store(p, v, __ATOMIC_RELAXED, __HIP_MEMORY_SCOPE_AGENT);
}
__device__ __forceinline__ void stu16_cc(u16* p, u16 v) {
  __hip_atomic_store(p, v, __ATOMIC_RELAXED, __HIP_MEMORY_SCOPE_AGENT);
}

// grid barrier with NO L2 invalidation (weights stay cached): drain vmcnt,
// release-add a counter, relaxed spin. R4-verbatim (correctness-proven).
__device__ __forceinline__ void gbar(unsigned* cnt, unsigned ep)
{
  asm volatile("s_waitcnt vmcnt(0)" ::: "memory");
  __syncthreads();
  if (threadIdx.x == 0) {
    __hip_atomic_fetch_add(cnt, 1u, __ATOMIC_RELEASE, __HIP_MEMORY_SCOPE_AGENT);
    while (__hip_atomic_load(cnt, __ATOMIC_RELAXED, __HIP_MEMORY_SCOPE_AGENT) < ep * 256u)
      __builtin_amdgcn_s_sleep(2);
  }
  __syncthreads();
  asm volatile("" ::: "memory");
}

// ---------------------------------------------------------------------------
// fp32 tiled GEMM for precompute: C[m][n] = act(sum_k A[m][k]*W[n][k])
// ---------------------------------------------------------------------------
__global__ __launch_bounds__(256) void gemm_pre_kernel(
    const float* __restrict__ A, int lda, const float* __restrict__ W, int ldw,
    float* __restrict__ C, u16* __restrict__ Cbf, int ldc, int K, int relu)
{
  __shared__ float As[16][66];
  __shared__ float Ws[16][66];
  const int tid = threadIdx.x;
  const int tn = tid & 15, tm = tid >> 4;
  const int n0 = blockIdx.x * 64;
  const int m0 = blockIdx.y * 64;
  float acc[4][4] = {{0.f}};
  for (int kt = 0; kt < K; kt += 16) {
#pragma unroll
    for (int i = 0; i < 4; i++) {
      int e = tid + 256 * i;
      int m = e >> 4, kk = e & 15;
      As[kk][m] = A[(size_t)(m0 + m) * lda + kt + kk];
    }
#pragma unroll
    for (int i = 0; i < 4; i++) {
      int e = tid + 256 * i;
      int n = e >> 4, kk = e & 15;
      Ws[kk][n] = W[(size_t)(n0 + n) * ldw + kt + kk];
    }
    __syncthreads();
#pragma unroll
    for (int kk = 0; kk < 16; kk++) {
      float2 a01 = *(const float2*)&As[kk][tm * 4];
      float2 a23 = *(const float2*)&As[kk][tm * 4 + 2];
      float2 w01 = *(const float2*)&Ws[kk][tn * 4];
      float2 w23 = *(const float2*)&Ws[kk][tn * 4 + 2];
      float a[4] = {a01.x, a01.y, a23.x, a23.y};
      float w[4] = {w01.x, w01.y, w23.x, w23.y};
#pragma unroll
      for (int mi = 0; mi < 4; mi++)
#pragma unroll
        for (int ni = 0; ni < 4; ni++)
          acc[mi][ni] = fmaf(a[mi], w[ni], acc[mi][ni]);
    }
    __syncthreads();
  }
#pragma unroll
  for (int mi = 0; mi < 4; mi++) {
    int m = m0 + tm * 4 + mi;
    float v0 = acc[mi][0], v1 = acc[mi][1], v2 = acc[mi][2], v3 = acc[mi][3];
    if (relu) {
      v0 = fmaxf(v0, 0.f); v1 = fmaxf(v1, 0.f);
      v2 = fmaxf(v2, 0.f); v3 = fmaxf(v3, 0.f);
    }
    if (Cbf) {
      u16* p = Cbf + (size_t)m * ldc + n0 + tn * 4;
      p[0] = f2bf(v0); p[1] = f2bf(v1); p[2] = f2bf(v2); p[3] = f2bf(v3);
    } else {
      float4 vv; vv.x = v0; vv.y = v1; vv.z = v2; vv.w = v3;
      *(float4*)&C[(size_t)m * ldc + n0 + tn * 4] = vv;
    }
  }
}

// ---------------------------------------------------------------------------
// Weight repack: W[n][k] fp32 -> bf16, MFMA B-fragment lane order.
// ---------------------------------------------------------------------------
__global__ __launch_bounds__(256) void pack_w_kernel(
    const float* __restrict__ W, u16* __restrict__ P,
    int K, int KTl, int ktOff, int KTtot, int total)
{
  int slot = blockIdx.x * 256 + threadIdx.x;
  if (slot >= total) return;
  int lane = slot & 63;
  int ktl = (slot >> 6) % KTl;
  int nt = slot / (64 * KTl);
  int n = nt * 16 + (lane & 15);
  int k = ktl * 32 + (lane >> 4) * 8;
  const float* src = W + (size_t)n * K + k;
  u16 tmp[8];
#pragma unroll
  for (int i = 0; i < 8; i++) tmp[i] = f2bf(src[i]);
  u16* dst = P + ((size_t)(nt * KTtot + (ktl + ktOff)) * 64 + lane) * 8;
  *(uint4*)dst = *(const uint4*)tmp;
}

// pm (b*t, a) -> pmT (b, a, t)
__global__ void transpose_pm_kernel(const float* __restrict__ pm, float* __restrict__ pmT)
{
  int b = blockIdx.z;
  int tT = blockIdx.x * 32, aT = blockIdx.y * 32;
  __shared__ float tile[32][33];
  int tx = threadIdx.x, ty = threadIdx.y;
#pragma unroll
  for (int i = 0; i < 4; i++) {
    int t = tT + ty + i * 8;
    int a = aT + tx;
    if (t < T_INN) tile[ty + i * 8][tx] = pm[((size_t)b * T_INN + t) * 128 + a];
  }
  __syncthreads();
#pragma unroll
  for (int i = 0; i < 4; i++) {
    int a = aT + ty + i * 8;
    int t = tT + tx;
    if (t < T_INN) pmT[((size_t)b * 128 + a) * T_INN + t] = tile[tx][ty + i * 8];
  }
}

// ---------------------------------------------------------------------------
// Shared-memory layouts
// ---------------------------------------------------------------------------
struct SmemGates {
  float part[16][16][66];   // [kw][gate*4+reg][lane(+pad)] conflict-free
  float gred[1024];
};
struct SmemAtt {
  float2 acS[T_INN];
  float ahS[1024];
  float pp[128][9];
  float pqS[128];
  float convS[T_INN][33];
  float ep[4][256];
  float red[8];
  float awS[256];
  float cpart[1024];
};
union SmemU { SmemGates g; SmemAtt a; };

struct DecParams {
  const u16* xs_bf;        // [400][64][256] read-only, cached
  const u16* Wa;           // packed, KT=64 — cached, L2-resident all steps
  const u16* Wd;           // packed, KT=80 — cached
  const float* b_a; const float* b_d;
  float* ah;               // f32 [64][1024] single copy (CC)
  float* dh;               // f32 [64][1024] single copy (CC)
  float* ac; float* dc;    // block-private, cached
  u16* ah_bf;              // [2][64][1024] parity (CC)
  u16* dh_bf;              // [2][64][1024] parity (CC)
  float* actx;             // [2][64][512] parity (CC)
  u16* actx_bf;            // [64][512] single (CC)
  float* aw; float* awcum; // attention-block-private, cached
  const float* pmT;
  const float* Wq; const float* Wconv; const float* Wloc; const float* vvec;
  const int* lens; const float* enc;
  const float* Wp; const float* bp;
  float* outsOut; float* alignsOut;
  unsigned* bar;
};

// R14 gates body with CC A-loads / CC h-stores. Weights NORMAL (cached).
// Z=0: gatesA KT=64 [xs|actx|ah|pad]; Z=1: gatesD KT=80 [ah|actx|dh].
template <int Z>
__device__ __forceinline__ void gates_body(
    const u16* __restrict__ xs, const u16* __restrict__ actx_bf,
    const u16* __restrict__ h1_bf, const u16* __restrict__ h2_bf,
    const u16* __restrict__ Wpack, const float* __restrict__ bias,
    float* __restrict__ hF, float* __restrict__ cSt, u16* __restrict__ hw,
    int bq, int ms2, int tid, SmemGates& sg)
{
  const int kw = tid >> 6, lane = tid & 63;
  const int mrow = lane & 15, ksub = (lane >> 4) * 8;
  const int rowL = ms2 * 32 + mrow;
  const int rowH = rowL + 16;

  f32x4 zero4 = {0.f, 0.f, 0.f, 0.f};
  f32x4 aL0 = zero4, aL1 = zero4, aL2 = zero4, aL3 = zero4;
  f32x4 aH0 = zero4, aH1 = zero4, aH2 = zero4, aH3 = zero4;

  if constexpr (Z == 0) {
    constexpr int KT = 64;
    const size_t gstride = (size_t)KT * 32768;
    const u16* wb0 = Wpack + ((size_t)(bq * KT + kw * 4) * 64 + lane) * 8;
    const u16* rbL; const u16* rbH;
    if (kw < 2) {
      rbL = xs + (size_t)rowL * 256 + ksub + kw * 128;
      rbH = xs + (size_t)rowH * 256 + ksub + kw * 128;
    } else if (kw < 6) {
      rbL = actx_bf + (size_t)rowL * 512 + ksub + kw * 128 - 256;
      rbH = actx_bf + (size_t)rowH * 512 + ksub + kw * 128 - 256;
    } else {
      rbL = h1_bf + (size_t)rowL * 1024 + ksub + kw * 128 - 768;
      rbH = h1_bf + (size_t)rowH * 1024 + ksub + kw * 128 - 768;
    }
#pragma unroll
    for (int i = 0; i < 4; i++) {
      bf16x8 al = ldbf8_cc(rbL + i * 32);
      bf16x8 ahi = ldbf8_cc(rbH + i * 32);
      const u16* wb = wb0 + (size_t)i * 512;
      bf16x8 w0 = ldbf8(wb);
      bf16x8 w1 = ldbf8(wb + gstride);
      bf16x8 w2 = ldbf8(wb + 2 * gstride);
      bf16x8 w3 = ldbf8(wb + 3 * gstride);
      aL0 = __builtin_amdgcn_mfma_f32_16x16x32_bf16(al, w0, aL0, 0, 0, 0);
      aL1 = __builtin_amdgcn_mfma_f32_16x16x32_bf16(al, w1, aL1, 0, 0, 0);
      aL2 = __builtin_amdgcn_mfma_f32_16x16x32_bf16(al, w2, aL2, 0, 0, 0);
      aL3 = __builtin_amdgcn_mfma_f32_16x16x32_bf16(al, w3, aL3, 0, 0, 0);
      aH0 = __builtin_amdgcn_mfma_f32_16x16x32_bf16(ahi, w0, aH0, 0, 0, 0);
      aH1 = __builtin_amdgcn_mfma_f32_16x16x32_bf16(ahi, w1, aH1, 0, 0, 0);
      aH2 = __builtin_amdgcn_mfma_f32_16x16x32_bf16(ahi, w2, aH2, 0, 0, 0);
      aH3 = __builtin_amdgcn_mfma_f32_16x16x32_bf16(ahi, w3, aH3, 0, 0, 0);
    }
  } else {
    constexpr int KT = 80;
    const size_t gstride = (size_t)KT * 32768;
    const u16* wb0 = Wpack + ((size_t)(bq * KT + kw) * 64 + lane) * 8;
    const u16* a0L = h1_bf   + (size_t)rowL * 1024 + ksub + kw * 32;
    const u16* a1L = actx_bf + (size_t)rowL * 512  + ksub + kw * 32;
    const u16* a2L = h2_bf   + (size_t)rowL * 1024 + ksub + kw * 32;
    const u16* a0H = h1_bf   + (size_t)rowH * 1024 + ksub + kw * 32;
    const u16* a1H = actx_bf + (size_t)rowH * 512  + ksub + kw * 32;
    const u16* a2H = h2_bf   + (size_t)rowH * 1024 + ksub + kw * 32;
#pragma unroll
    for (int i = 0; i < 5; i++) {
      const u16* apL = (i < 2) ? (a0L + i * 512) : ((i == 2) ? a1L : (a2L + (i - 3) * 512));
      const u16* apH = (i < 2) ? (a0H + i * 512) : ((i == 2) ? a1H : (a2H + (i - 3) * 512));
      bf16x8 al = ldbf8_cc(apL);
      bf16x8 ahi = ldbf8_cc(apH);
      const u16* wb = wb0 + (size_t)i * (16 * 512);
      bf16x8 w0 = ldbf8(wb);
      bf16x8 w1 = ldbf8(wb + gstride);
      bf16x8 w2 = ldbf8(wb + 2 * gstride);
      bf16x8 w3 = ldbf8(wb + 3 * gstride);
      aL0 = __builtin_amdgcn_mfma_f32_16x16x32_bf16(al, w0, aL0, 0, 0, 0);
      aL1 = __builtin_amdgcn_mfma_f32_16x16x32_bf16(al, w1, aL1, 0, 0, 0);
      aL2 = __builtin_amdgcn_mfma_f32_16x16x32_bf16(al, w2, aL2, 0, 0, 0);
      aL3 = __builtin_amdgcn_mfma_f32_16x16x32_bf16(al, w3, aL3, 0, 0, 0);
      aH0 = __builtin_amdgcn_mfma_f32_16x16x32_bf16(ahi, w0, aH0, 0, 0, 0);
      aH1 = __builtin_amdgcn_mfma_f32_16x16x32_bf16(ahi, w1, aH1, 0, 0, 0);
      aH2 = __builtin_amdgcn_mfma_f32_16x16x32_bf16(ahi, w2, aH2, 0, 0, 0);
      aH3 = __builtin_amdgcn_mfma_f32_16x16x32_bf16(ahi, w3, aH3, 0, 0, 0);
    }
  }

  // epilogue twice (lo rows, hi rows), reusing the same LDS buffer
#pragma unroll
  for (int h = 0; h < 2; h++) {
    if (h == 1) __syncthreads();
#pragma unroll
    for (int r = 0; r < 4; r++) {
      if (h == 0) {
        sg.part[kw][r][lane]      = aL0[r];
        sg.part[kw][4 + r][lane]  = aL1[r];
        sg.part[kw][8 + r][lane]  = aL2[r];
        sg.part[kw][12 + r][lane] = aL3[r];
      } else {
        sg.part[kw][r][lane]      = aH0[r];
        sg.part[kw][4 + r][lane]  = aH1[r];
        sg.part[kw][8 + r][lane]  = aH2[r];
        sg.part[kw][12 + r][lane] = aH3[r];
      }
    }
    __syncthreads();
    {
      int g = tid >> 8, rc = tid & 255, rw = rc >> 4, col = rc & 15;
      int ln = ((rw >> 2) << 4) + col;
      int r = g * 4 + (rw & 3);
      float s = 0.f;
#pragma unroll
      for (int k2 = 0; k2 < 16; k2++) s += sg.part[k2][r][ln];
      sg.gred[tid] = s;
    }
    __syncthreads();
    if (tid < 256) {
      int rw = tid >> 4, col = tid & 15;
      int j = bq * 16 + col, m = ms2 * 32 + h * 16 + rw;
      size_t idx = (size_t)m * 1024 + j;
      float gi = sg.gred[tid]       + bias[j];
      float gf = sg.gred[256 + tid] + bias[j + 1024];
      float gg = sg.gred[512 + tid] + bias[j + 2048];
      float go = sg.gred[768 + tid] + bias[j + 3072];
      float cn = sigf(gf) * cSt[idx] + sigf(gi) * ftanh(gg);
      cSt[idx] = cn;                       // block-private: cached
      float hn = sigf(go) * ftanh(cn);
      stf_cc(&hF[idx], hn);
      stu16_cc(&hw[idx], f2bf(hn));
    }
  }
}

// ---------------------------------------------------------------------------
// Persistent decode kernel, 256 blocks x 1024 threads, cooperative launch
// for co-residency. NO grid.sync (no L2 invalidation) — custom LLC barrier.
// Per step t: phase A = gatesA(t) [blocks 0-127] || gatesD(t-1) [128-255]
//             gbar
//             phase B = attention(t) [0-63] || outproj(t-1) [64-127]
//             gbar
// ---------------------------------------------------------------------------
__global__ __launch_bounds__(1024, 4) void decode_kernel(DecParams p)
{
  const int b = blockIdx.x;
  const int tid = threadIdx.x;
  const int g = tid >> 8, ti = tid & 255;
  __shared__ SmemU sm;
  unsigned ep = 0;

  for (int t = 0; t <= T_OUTT; t++) {
    // ---------------- phase A ----------------
    if (b < 128) {
      if (t < T_OUTT)
        gates_body<0>(p.xs_bf + (size_t)t * 64 * 256,
                      p.actx_bf,
                      p.ah_bf + (size_t)((t + 1) & 1) * 65536, nullptr,
                      p.Wa, p.b_a, p.ah, p.ac,
                      p.ah_bf + (size_t)(t & 1) * 65536,
                      b & 63, b >> 6, tid, sm.g);
    } else {
      if (t >= 1)
        gates_body<1>(nullptr,
                      p.actx_bf,
                      p.ah_bf + (size_t)((t + 1) & 1) * 65536,
                      p.dh_bf + (size_t)(t & 1) * 65536,
                      p.Wd, p.b_d, p.dh, p.dc,
                      p.dh_bf + (size_t)((t + 1) & 1) * 65536,
                      (b - 128) & 63, (b - 128) >> 6, tid, sm.g);
    }
    gbar(p.bar, ++ep);

    // ---------------- phase B ----------------
    if (b < 64) {
      if (t < T_OUTT) {
        SmemAtt& sa = sm.a;
        float* actxW = p.actx + (size_t)(t & 1) * 32768;
        if (tid < T_INN) {
          float2 v; v.x = p.aw[b * T_INN + tid]; v.y = p.awcum[b * T_INN + tid];
          sa.acS[tid] = v;
        }
        sa.ahS[tid] = ldf_cc(&p.ah[(size_t)b * 1024 + tid]);
        __syncthreads();
        {
          int a = tid >> 3, kc = tid & 7;
          const float4* wv = (const float4*)(p.Wq + (size_t)a * 1024 + kc * 128);
          const float4* hv = (const float4*)(sa.ahS + kc * 128);
          float s = 0.f;
#pragma unroll 8
          for (int i = 0; i < 32; i++) {
            float4 wq = wv[i], hh = hv[i];
            s += wq.x * hh.x + wq.y * hh.y + wq.z * hh.z + wq.w * hh.w;
          }
          sa.pp[a][kc] = s;
        }
        __syncthreads();
        if (tid < 128) {
          float s = 0.f;
#pragma unroll
          for (int kc = 0; kc < 8; kc++) s += sa.pp[tid][kc];
          sa.pqS[tid] = s;
        }
        if (ti < T_INN) {
          float sacc[8] = {0.f, 0.f, 0.f, 0.f, 0.f, 0.f, 0.f, 0.f};
#pragma unroll
          for (int k = 0; k < 31; k++) {
            int tt = ti + k - 15;
            if (tt >= 0 && tt < T_INN) {
              float2 v = sa.acS[tt];
#pragma unroll
              for (int f8 = 0; f8 < 8; f8++) {
                int f = g * 8 + f8;
                sacc[f8] += p.Wconv[f * 62 + k] * v.x + p.Wconv[f * 62 + 31 + k] * v.y;
              }
            }
          }
#pragma unroll
          for (int f8 = 0; f8 < 8; f8++) sa.convS[ti][g * 8 + f8] = sacc[f8];
        }
        __syncthreads();
        float e = 0.f;
        if (ti < T_INN) {
          float cv[32];
#pragma unroll
          for (int f = 0; f < 32; f++) cv[f] = sa.convS[ti][f];
          const float* pm = p.pmT + ((size_t)b * 128 + g * 32) * T_INN + ti;
#pragma unroll 4
          for (int aa = 0; aa < 32; aa++) {
            int a = g * 32 + aa;
            float x = sa.pqS[a] + pm[(size_t)aa * T_INN];
            const float* wl = p.Wloc + a * 32;
#pragma unroll
            for (int f = 0; f < 32; f++) x += wl[f] * cv[f];
            float ex2 = __expf(2.f * x);
            e += p.vvec[a] * (1.f - 2.f * __builtin_amdgcn_rcpf(ex2 + 1.f));
          }
        }
        sa.ep[g][ti] = e;
        __syncthreads();
        float ev = -3.0e38f;
        if (tid < 256) {
          if (tid < T_INN) {
            ev = sa.ep[0][tid] + sa.ep[1][tid] + sa.ep[2][tid] + sa.ep[3][tid];
            if (tid >= p.lens[b]) ev = -100000000.0f;
          }
        }
        float mloc = ev;
#pragma unroll
        for (int o = 32; o > 0; o >>= 1) mloc = fmaxf(mloc, __shfl_xor(mloc, o));
        if (tid < 256 && (tid & 63) == 0) sa.red[tid >> 6] = mloc;
        __syncthreads();
        float mx = fmaxf(fmaxf(sa.red[0], sa.red[1]), fmaxf(sa.red[2], sa.red[3]));
        float ex = (tid < T_INN) ? __expf(ev - mx) : 0.f;
        float sloc = ex;
#pragma unroll
        for (int o = 32; o > 0; o >>= 1) sloc += __shfl_xor(sloc, o);
        if (tid < 256 && (tid & 63) == 0) sa.red[4 + (tid >> 6)] = sloc;
        __syncthreads();
        float inv = 1.0f / ((sa.red[4] + sa.red[5]) + (sa.red[6] + sa.red[7]));
        if (tid < T_INN) {
          float a = ex * inv;
          sa.awS[tid] = a;
          p.aw[b * T_INN + tid] = a;                       // private: cached
          p.awcum[b * T_INN + tid] = sa.acS[tid].y + a;
          p.alignsOut[((size_t)b * T_OUTT + t) * T_INN + tid] = a;
        }
        __syncthreads();
        {
          int e0 = tid & 511, half = tid >> 9;
          const float* ep2 = p.enc + ((size_t)b * T_INN + half * 100) * DENC + e0;
          float s = 0.f;
#pragma unroll 4
          for (int tt = 0; tt < 100; tt++)
            s += sa.awS[half * 100 + tt] * ep2[(size_t)tt * DENC];
          sa.cpart[tid] = s;
        }
        __syncthreads();
        if (tid < 512) {
          float v2 = sa.cpart[tid] + sa.cpart[512 + tid];
          stf_cc(&actxW[b * DENC + tid], v2);
          stu16_cc(&p.actx_bf[b * DENC + tid], f2bf(v2));
        }
      }
    } else if (b < 128) {
      if (t >= 1) {
        const int bo = b - 64;
        const float* actxR = p.actx + (size_t)((t - 1) & 1) * 32768;
        float* cp = sm.g.gred;
        float s = 0.f;
        int m = tid / 12, sub = tid - m * 12;
        if (tid < 960) {
          const float4* w4 = (const float4*)(p.Wp + (size_t)m * 1536 + sub * 128);
          const float* aBase = (sub < 8)
              ? (p.dh + (size_t)bo * 1024 + sub * 128)
              : (actxR + (size_t)bo * 512 + (sub - 8) * 128);
#pragma unroll 8
          for (int kk = 0; kk < 32; kk++) {
            float4 w = w4[kk];
            float4 av = ldf4_cc(aBase + kk * 4);
            s += w.x * av.x + w.y * av.y + w.z * av.z + w.w * av.w;
          }
        }
        cp[tid] = s;
        __syncthreads();
        if (tid < 80) {
          float acc2 = p.bp[tid];
#pragma unroll
          for (int i2 = 0; i2 < 12; i2++) acc2 += cp[tid * 12 + i2];
          p.outsOut[((size_t)bo * T_OUTT + (t - 1)) * NMEL + tid] = acc2;
        }
      }
    }
    if (t == T_OUTT) break;
    gbar(p.bar, ++ep);
  }
}

extern "C" void kernel_launch(void* const* d_in, const int* in_sizes, int n_in,
                              void* d_out, int out_size, void* d_ws, size_t ws_size,
                              hipStream_t stream)
{
  const float* enc    = (const float*)d_in[0];
  const float* dec    = (const float*)d_in[1];
  const int*   lens   = (const int*)d_in[2];
  const float* W_p1   = (const float*)d_in[3];
  const float* W_p2   = (const float*)d_in[4];
  const float* W_ih_a = (const float*)d_in[5];
  const float* W_hh_a = (const float*)d_in[6];
  const float* b_a    = (const float*)d_in[7];
  const float* Wq     = (const float*)d_in[8];
  const float* Wmem   = (const float*)d_in[9];
  const float* vvec   = (const float*)d_in[10];
  const float* Wconv  = (const float*)d_in[11];
  const float* Wloc   = (const float*)d_in[12];
  const float* W_ih_d = (const float*)d_in[13];
  const float* W_hh_d = (const float*)d_in[14];
  const float* b_d    = (const float*)d_in[15];
  const float* Wp     = (const float*)d_in[16];
  const float* bp     = (const float*)d_in[17];

  float* ws = (float*)d_ws;
  size_t off = 0;
  u16* xs_bf = (u16*)(ws + off); off += (size_t)T_OUTT * 64 * 256 / 2;
  float* pmT = ws + off; off += (size_t)64 * 128 * T_INN;
  u16* Wa_pack = (u16*)(ws + off); off += (size_t)4096 * 2048 / 2;   // KT=64 padded
  u16* Wd_pack = (u16*)(ws + off); off += (size_t)4096 * 2560 / 2;   // KT=80
  // state block (zero-initialized)
  float* stateBase = ws + off;
  float* ah    = stateBase;            // f32 [64][1024]
  float* dh    = ah + 65536;           // f32 [64][1024]
  float* ac    = dh + 65536;
  float* dc    = ac + 65536;
  float* actx  = dc + 65536;           // [2][64][512] parity
  float* aw    = actx + 2 * 32768;
  float* awcum = aw + 12800;
  u16* ah_bf   = (u16*)(awcum + 12800);     // [2][64][1024]
  u16* dh_bf   = ah_bf + 2 * 65536;         // [2][64][1024]
  u16* actx_bf = dh_bf + 2 * 65536;         // [64][512]
  unsigned* barCnt = (unsigned*)(actx_bf + 32768);   // 16B, zeroed
  size_t stateFloats = 4 * 65536 + 2 * 32768 + 2 * 12800
                     + (2 * 65536 + 2 * 65536 + 32768) / 2 + 16;
  off += stateFloats;
  float* scratch = ws + off;           // precompute only
  float* h1 = scratch;                 // 399*64 x 256
  float* pmt = scratch;                // reused after prenet

  float* outsOut   = (float*)d_out;
  float* alignsOut = outsOut + (size_t)BB * T_OUTT * NMEL;

  // zero recurrent state + barrier + t=0 prenet row; zero Wa_pack padding
  hipMemsetAsync(stateBase, 0, stateFloats * sizeof(float), stream);
  hipMemsetAsync(xs_bf, 0, (size_t)64 * 256 * sizeof(u16), stream);
  hipMemsetAsync(Wa_pack, 0, (size_t)4096 * 2048 * sizeof(u16), stream);

  // ---- precompute ----
  {
    int tot;
    tot = 256 * 24 * 64;
    pack_w_kernel<<<(tot + 255) / 256, 256, 0, stream>>>(W_ih_a, Wa_pack, 768, 24, 0, 64, tot);
    tot = 256 * 32 * 64;
    pack_w_kernel<<<(tot + 255) / 256, 256, 0, stream>>>(W_hh_a, Wa_pack, 1024, 32, 24, 64, tot);
    tot = 256 * 48 * 64;
    pack_w_kernel<<<(tot + 255) / 256, 256, 0, stream>>>(W_ih_d, Wd_pack, 1536, 48, 0, 80, tot);
    tot = 256 * 32 * 64;
    pack_w_kernel<<<(tot + 255) / 256, 256, 0, stream>>>(W_hh_d, Wd_pack, 1024, 32, 48, 80, tot);
  }
  gemm_pre_kernel<<<dim3(4, 399), 256, 0, stream>>>(dec, 80, W_p1, 80, h1, nullptr, 256, 80, 1);
  gemm_pre_kernel<<<dim3(4, 399), 256, 0, stream>>>(h1, 256, W_p2, 256, nullptr, xs_bf + 64 * 256, 256, 256, 1);
  gemm_pre_kernel<<<dim3(2, 200), 256, 0, stream>>>(enc, 512, Wmem, 512, pmt, nullptr, 128, 512, 0);
  transpose_pm_kernel<<<dim3(7, 4, 64), dim3(32, 8), 0, stream>>>(pmt, pmT);

  // ---- persistent decode (1 dispatch for all 400 steps) ----
  DecParams dp;
  dp.xs_bf = xs_bf; dp.Wa = Wa_pack; dp.Wd = Wd_pack;
  dp.b_a = b_a; dp.b_d = b_d;
  dp.ah = ah; dp.dh = dh; dp.ac = ac; dp.dc = dc;
  dp.ah_bf = ah_bf; dp.dh_bf = dh_bf;
  dp.actx = actx; dp.actx_bf = actx_bf;
  dp.aw = aw; dp.awcum = awcum;
  dp.pmT = pmT; dp.Wq = Wq; dp.Wconv = Wconv; dp.Wloc = Wloc; dp.vvec = vvec;
  dp.lens = lens; dp.enc = enc; dp.Wp = Wp; dp.bp = bp;
  dp.outsOut = outsOut; dp.alignsOut = alignsOut;
  dp.bar = barCnt;

  void* kargs[] = { (void*)&dp };
  hipLaunchCooperativeKernel(decode_kernel, dim3(256), dim3(1024), kargs, 0, stream);
}

// Round 16
// 33686.673 us; speedup vs baseline: 1.7178x; 1.7178x over previous
//
#include <hip/hip_runtime.h>
#include <cstddef>
#include <cstdint>

#define T_INN 200
#define T_OUTT 400
#define BB 64
#define DENC 512
#define NMEL 80

typedef unsigned short u16;
typedef __bf16 bf16x8 __attribute__((ext_vector_type(8)));
typedef float f32x4 __attribute__((ext_vector_type(4)));

// fast sigmoid/tanh (validated R5-R14: absmax unchanged at 0.00098)
__device__ __forceinline__ float sigf(float x) {
  return __builtin_amdgcn_rcpf(1.0f + __expf(-x));
}
__device__ __forceinline__ float ftanh(float x) {
  float e2 = __expf(2.0f * x);
  return 1.0f - 2.0f * __builtin_amdgcn_rcpf(e2 + 1.0f);
}

// round-to-nearest-even f32 -> bf16
__device__ __forceinline__ u16 f2bf(float f) {
  unsigned u = __float_as_uint(f);
  unsigned r = u + 0x7fffu + ((u >> 16) & 1u);
  return (u16)(r >> 16);
}

__device__ __forceinline__ bf16x8 ldbf8(const u16* p) { return *(const bf16x8*)p; }

// ---------------------------------------------------------------------------
// fp32 tiled GEMM for precompute: C[m][n] = act(sum_k A[m][k]*W[n][k])
// ---------------------------------------------------------------------------
__global__ __launch_bounds__(256) void gemm_pre_kernel(
    const float* __restrict__ A, int lda, const float* __restrict__ W, int ldw,
    float* __restrict__ C, u16* __restrict__ Cbf, int ldc, int K, int relu)
{
  __shared__ float As[16][66];
  __shared__ float Ws[16][66];
  const int tid = threadIdx.x;
  const int tn = tid & 15, tm = tid >> 4;
  const int n0 = blockIdx.x * 64;
  const int m0 = blockIdx.y * 64;
  float acc[4][4] = {{0.f}};
  for (int kt = 0; kt < K; kt += 16) {
#pragma unroll
    for (int i = 0; i < 4; i++) {
      int e = tid + 256 * i;
      int m = e >> 4, kk = e & 15;
      As[kk][m] = A[(size_t)(m0 + m) * lda + kt + kk];
    }
#pragma unroll
    for (int i = 0; i < 4; i++) {
      int e = tid + 256 * i;
      int n = e >> 4, kk = e & 15;
      Ws[kk][n] = W[(size_t)(n0 + n) * ldw + kt + kk];
    }
    __syncthreads();
#pragma unroll
    for (int kk = 0; kk < 16; kk++) {
      float2 a01 = *(const float2*)&As[kk][tm * 4];
      float2 a23 = *(const float2*)&As[kk][tm * 4 + 2];
      float2 w01 = *(const float2*)&Ws[kk][tn * 4];
      float2 w23 = *(const float2*)&Ws[kk][tn * 4 + 2];
      float a[4] = {a01.x, a01.y, a23.x, a23.y};
      float w[4] = {w01.x, w01.y, w23.x, w23.y};
#pragma unroll
      for (int mi = 0; mi < 4; mi++)
#pragma unroll
        for (int ni = 0; ni < 4; ni++)
          acc[mi][ni] = fmaf(a[mi], w[ni], acc[mi][ni]);
    }
    __syncthreads();
  }
#pragma unroll
  for (int mi = 0; mi < 4; mi++) {
    int m = m0 + tm * 4 + mi;
    float v0 = acc[mi][0], v1 = acc[mi][1], v2 = acc[mi][2], v3 = acc[mi][3];
    if (relu) {
      v0 = fmaxf(v0, 0.f); v1 = fmaxf(v1, 0.f);
      v2 = fmaxf(v2, 0.f); v3 = fmaxf(v3, 0.f);
    }
    if (Cbf) {
      u16* p = Cbf + (size_t)m * ldc + n0 + tn * 4;
      p[0] = f2bf(v0); p[1] = f2bf(v1); p[2] = f2bf(v2); p[3] = f2bf(v3);
    } else {
      float4 vv; vv.x = v0; vv.y = v1; vv.z = v2; vv.w = v3;
      *(float4*)&C[(size_t)m * ldc + n0 + tn * 4] = vv;
    }
  }
}

// ---------------------------------------------------------------------------
// Weight repack: W[n][k] fp32 -> bf16, MFMA B-fragment lane order.
// ---------------------------------------------------------------------------
__global__ __launch_bounds__(256) void pack_w_kernel(
    const float* __restrict__ W, u16* __restrict__ P,
    int K, int KTl, int ktOff, int KTtot, int total)
{
  int slot = blockIdx.x * 256 + threadIdx.x;
  if (slot >= total) return;
  int lane = slot & 63;
  int ktl = (slot >> 6) % KTl;
  int nt = slot / (64 * KTl);
  int n = nt * 16 + (lane & 15);
  int k = ktl * 32 + (lane >> 4) * 8;
  const float* src = W + (size_t)n * K + k;
  u16 tmp[8];
#pragma unroll
  for (int i = 0; i < 8; i++) tmp[i] = f2bf(src[i]);
  u16* dst = P + ((size_t)(nt * KTtot + (ktl + ktOff)) * 64 + lane) * 8;
  *(uint4*)dst = *(const uint4*)tmp;
}

// pm (b*t, a) -> pmT (b, a, t)
__global__ void transpose_pm_kernel(const float* __restrict__ pm, float* __restrict__ pmT)
{
  int b = blockIdx.z;
  int tT = blockIdx.x * 32, aT = blockIdx.y * 32;
  __shared__ float tile[32][33];
  int tx = threadIdx.x, ty = threadIdx.y;
#pragma unroll
  for (int i = 0; i < 4; i++) {
    int t = tT + ty + i * 8;
    int a = aT + tx;
    if (t < T_INN) tile[ty + i * 8][tx] = pm[((size_t)b * T_INN + t) * 128 + a];
  }
  __syncthreads();
#pragma unroll
  for (int i = 0; i < 4; i++) {
    int a = aT + ty + i * 8;
    int t = tT + tx;
    if (t < T_INN) pmT[((size_t)b * 128 + a) * T_INN + t] = tile[tx][ty + i * 8];
  }
}

// ---------------------------------------------------------------------------
// Gates + LSTM activation. grid (64 quads, 2 m-pairs, 2 gate-types), 1024
// threads (16 waves, split-K over waves, LDS reduce). Each block covers 32
// rows; weights loaded once per block (dedup).
// z=0: gatesA(t) KT=64 (zero-padded from 56); z=1: gatesD(t-1) KT=80.
// ---------------------------------------------------------------------------
struct SmemGates {
  float part[16][16][66];   // [kw][gate*4+reg][lane(+pad)] conflict-free
  float gred[1024];
};

__global__ __launch_bounds__(1024, 4) void gates_kernel(
    const u16* __restrict__ xs,        // [64][256] prenet rows for step t
    const u16* __restrict__ actx_bf,   // [64][512]
    const u16* __restrict__ ah_bf_r, u16* __restrict__ ah_bf_w,
    const u16* __restrict__ dh_bf_r, u16* __restrict__ dh_bf_w,
    const u16* __restrict__ Wa, const u16* __restrict__ Wd,
    const float* __restrict__ b_a, const float* __restrict__ b_d,
    float* __restrict__ ah, float* __restrict__ ac,
    float* __restrict__ dh, float* __restrict__ dc, int t)
{
  const int z = blockIdx.z;
  if (z == 0 && t >= T_OUTT) return;
  if (z == 1 && t < 1) return;
  const int bq = blockIdx.x, ms2 = blockIdx.y;   // rows ms2*32 .. ms2*32+31
  const int tid = threadIdx.x;
  const int kw = tid >> 6, lane = tid & 63;
  const int mrow = lane & 15, ksub = (lane >> 4) * 8;
  const int rowL = ms2 * 32 + mrow;
  const int rowH = rowL + 16;
  __shared__ SmemGates sg;

  f32x4 zero4 = {0.f, 0.f, 0.f, 0.f};
  f32x4 aL0 = zero4, aL1 = zero4, aL2 = zero4, aL3 = zero4;
  f32x4 aH0 = zero4, aH1 = zero4, aH2 = zero4, aH3 = zero4;
  const float* bias; float* hF; float* cSt; u16* hw;

  if (z == 0) {
    // gatesA(t): A = [xs(256) | actx(512) | ah(1024) | pad(256, W=0)], KT=64
    constexpr int KT = 64;
    const size_t gstride = (size_t)KT * 32768;
    const u16* wb0 = Wa + ((size_t)(bq * KT + kw * 4) * 64 + lane) * 8;
    const u16* rbL; const u16* rbH;
    if (kw < 2) {
      rbL = xs + (size_t)rowL * 256 + ksub + kw * 128;
      rbH = xs + (size_t)rowH * 256 + ksub + kw * 128;
    } else if (kw < 6) {
      rbL = actx_bf + (size_t)rowL * 512 + ksub + kw * 128 - 256;
      rbH = actx_bf + (size_t)rowH * 512 + ksub + kw * 128 - 256;
    } else {
      rbL = ah_bf_r + (size_t)rowL * 1024 + ksub + kw * 128 - 768;
      rbH = ah_bf_r + (size_t)rowH * 1024 + ksub + kw * 128 - 768;
    }
#pragma unroll
    for (int i = 0; i < 4; i++) {
      bf16x8 al = ldbf8(rbL + i * 32);
      bf16x8 ahi = ldbf8(rbH + i * 32);
      const u16* wb = wb0 + (size_t)i * 512;
      bf16x8 w0 = ldbf8(wb);
      bf16x8 w1 = ldbf8(wb + gstride);
      bf16x8 w2 = ldbf8(wb + 2 * gstride);
      bf16x8 w3 = ldbf8(wb + 3 * gstride);
      aL0 = __builtin_amdgcn_mfma_f32_16x16x32_bf16(al, w0, aL0, 0, 0, 0);
      aL1 = __builtin_amdgcn_mfma_f32_16x16x32_bf16(al, w1, aL1, 0, 0, 0);
      aL2 = __builtin_amdgcn_mfma_f32_16x16x32_bf16(al, w2, aL2, 0, 0, 0);
      aL3 = __builtin_amdgcn_mfma_f32_16x16x32_bf16(al, w3, aL3, 0, 0, 0);
      aH0 = __builtin_amdgcn_mfma_f32_16x16x32_bf16(ahi, w0, aH0, 0, 0, 0);
      aH1 = __builtin_amdgcn_mfma_f32_16x16x32_bf16(ahi, w1, aH1, 0, 0, 0);
      aH2 = __builtin_amdgcn_mfma_f32_16x16x32_bf16(ahi, w2, aH2, 0, 0, 0);
      aH3 = __builtin_amdgcn_mfma_f32_16x16x32_bf16(ahi, w3, aH3, 0, 0, 0);
    }
    bias = b_a; hF = ah; cSt = ac; hw = ah_bf_w;
  } else {
    // gatesD(t-1): A = [ah(1024) | actx(512) | dh(1024)], KT=80
    constexpr int KT = 80;
    const size_t gstride = (size_t)KT * 32768;
    const u16* wb0 = Wd + ((size_t)(bq * KT + kw) * 64 + lane) * 8;
    const u16* a0L = ah_bf_r + (size_t)rowL * 1024 + ksub + kw * 32;
    const u16* a1L = actx_bf + (size_t)rowL * 512  + ksub + kw * 32;
    const u16* a2L = dh_bf_r + (size_t)rowL * 1024 + ksub + kw * 32;
    const u16* a0H = ah_bf_r + (size_t)rowH * 1024 + ksub + kw * 32;
    const u16* a1H = actx_bf + (size_t)rowH * 512  + ksub + kw * 32;
    const u16* a2H = dh_bf_r + (size_t)rowH * 1024 + ksub + kw * 32;
#pragma unroll
    for (int i = 0; i < 5; i++) {
      const u16* apL = (i < 2) ? (a0L + i * 512) : ((i == 2) ? a1L : (a2L + (i - 3) * 512));
      const u16* apH = (i < 2) ? (a0H + i * 512) : ((i == 2) ? a1H : (a2H + (i - 3) * 512));
      bf16x8 al = ldbf8(apL);
      bf16x8 ahi = ldbf8(apH);
      const u16* wb = wb0 + (size_t)i * (16 * 512);
      bf16x8 w0 = ldbf8(wb);
      bf16x8 w1 = ldbf8(wb + gstride);
      bf16x8 w2 = ldbf8(wb + 2 * gstride);
      bf16x8 w3 = ldbf8(wb + 3 * gstride);
      aL0 = __builtin_amdgcn_mfma_f32_16x16x32_bf16(al, w0, aL0, 0, 0, 0);
      aL1 = __builtin_amdgcn_mfma_f32_16x16x32_bf16(al, w1, aL1, 0, 0, 0);
      aL2 = __builtin_amdgcn_mfma_f32_16x16x32_bf16(al, w2, aL2, 0, 0, 0);
      aL3 = __builtin_amdgcn_mfma_f32_16x16x32_bf16(al, w3, aL3, 0, 0, 0);
      aH0 = __builtin_amdgcn_mfma_f32_16x16x32_bf16(ahi, w0, aH0, 0, 0, 0);
      aH1 = __builtin_amdgcn_mfma_f32_16x16x32_bf16(ahi, w1, aH1, 0, 0, 0);
      aH2 = __builtin_amdgcn_mfma_f32_16x16x32_bf16(ahi, w2, aH2, 0, 0, 0);
      aH3 = __builtin_amdgcn_mfma_f32_16x16x32_bf16(ahi, w3, aH3, 0, 0, 0);
    }
    bias = b_d; hF = dh; cSt = dc; hw = dh_bf_w;
  }

  // epilogue twice (lo rows, hi rows), reusing the same LDS buffer
#pragma unroll
  for (int h = 0; h < 2; h++) {
    if (h == 1) __syncthreads();
#pragma unroll
    for (int r = 0; r < 4; r++) {
      if (h == 0) {
        sg.part[kw][r][lane]      = aL0[r];
        sg.part[kw][4 + r][lane]  = aL1[r];
        sg.part[kw][8 + r][lane]  = aL2[r];
        sg.part[kw][12 + r][lane] = aL3[r];
      } else {
        sg.part[kw][r][lane]      = aH0[r];
        sg.part[kw][4 + r][lane]  = aH1[r];
        sg.part[kw][8 + r][lane]  = aH2[r];
        sg.part[kw][12 + r][lane] = aH3[r];
      }
    }
    __syncthreads();
    {
      int g = tid >> 8, rc = tid & 255, rw = rc >> 4, col = rc & 15;
      int ln = ((rw >> 2) << 4) + col;
      int r = g * 4 + (rw & 3);
      float s = 0.f;
#pragma unroll
      for (int k2 = 0; k2 < 16; k2++) s += sg.part[k2][r][ln];
      sg.gred[tid] = s;
    }
    __syncthreads();
    if (tid < 256) {
      int rw = tid >> 4, col = tid & 15;
      int j = bq * 16 + col, m = ms2 * 32 + h * 16 + rw;
      size_t idx = (size_t)m * 1024 + j;
      float gi = sg.gred[tid]       + bias[j];
      float gf = sg.gred[256 + tid] + bias[j + 1024];
      float gg = sg.gred[512 + tid] + bias[j + 2048];
      float go = sg.gred[768 + tid] + bias[j + 3072];
      float cn = sigf(gf) * cSt[idx] + sigf(gi) * ftanh(gg);
      cSt[idx] = cn;
      float hn = sigf(go) * ftanh(cn);
      hF[idx] = hn;
      hw[idx] = f2bf(hn);
    }
  }
}

// ---------------------------------------------------------------------------
// Fused step kernel (+ shuffle softmax): grid 128, launch_bounds(1024,4).
//   b in [0,64):   attention(t) for batch b        [skip t==400]
//   b in [64,128): outproj(t-1) for batch b-64     [skip t==0]
// Softmax: per-wave __shfl_xor reduce + 4-partial LDS combine — 2 barriers.
// ---------------------------------------------------------------------------
__global__ __launch_bounds__(1024, 4) void fused_step_kernel(
    const float* __restrict__ ah, const float* __restrict__ dh,
    float* __restrict__ actx /*[2][64][512]*/, u16* __restrict__ actx_bf,
    float* __restrict__ aw, float* __restrict__ awcum,
    const float* __restrict__ pmT, const float* __restrict__ Wq,
    const float* __restrict__ Wconv, const float* __restrict__ Wloc,
    const float* __restrict__ vvec, const int* __restrict__ lens,
    const float* __restrict__ enc, const float* __restrict__ Wp,
    const float* __restrict__ bp,
    float* __restrict__ outsOut, float* __restrict__ alignsOut, int t)
{
  const int tid = threadIdx.x;

  if (blockIdx.x >= 64) {
    // ---- outproj(t-1) ----
    if (t < 1) return;
    const int bo = blockIdx.x - 64;
    const float* actxR = actx + (size_t)((t - 1) & 1) * 32768;
    __shared__ float cp[1024];
    float s = 0.f;
    int m = tid / 12, sub = tid - m * 12;
    if (tid < 960) {
      const float4* w4 = (const float4*)(Wp + (size_t)m * 1536 + sub * 128);
      const float4* a4 = (sub < 8)
          ? (const float4*)(dh + (size_t)bo * 1024 + sub * 128)
          : (const float4*)(actxR + (size_t)bo * 512 + (sub - 8) * 128);
#pragma unroll 8
      for (int kk = 0; kk < 32; kk++) {
        float4 w = w4[kk], av = a4[kk];
        s += w.x * av.x + w.y * av.y + w.z * av.z + w.w * av.w;
      }
    }
    cp[tid] = s;
    __syncthreads();
    if (tid < 80) {
      float acc2 = bp[tid];
#pragma unroll
      for (int i2 = 0; i2 < 12; i2++) acc2 += cp[tid * 12 + i2];
      outsOut[((size_t)bo * T_OUTT + (t - 1)) * NMEL + tid] = acc2;
    }
    return;
  }

  // ---- attention(t) ----
  if (t >= T_OUTT) return;
  const int b = blockIdx.x;
  const int g = tid >> 8, ti = tid & 255;
  float* actxW = actx + (size_t)(t & 1) * 32768;

  __shared__ float2 acS[T_INN];        // (aw, awcum) merged -> ds_read_b64
  __shared__ float ahS[1024];
  __shared__ float pp[128][9];
  __shared__ float pqS[128];
  __shared__ float convS[T_INN][33];
  __shared__ float ep[4][256];
  __shared__ float red[8];
  __shared__ float awS[256];
  __shared__ float cpart[1024];

  if (tid < T_INN) {
    float2 v; v.x = aw[b * T_INN + tid]; v.y = awcum[b * T_INN + tid];
    acS[tid] = v;
  }
  ahS[tid] = ah[(size_t)b * 1024 + tid];
  __syncthreads();
  {
    int a = tid >> 3, kc = tid & 7;
    const float4* wv = (const float4*)(Wq + (size_t)a * 1024 + kc * 128);
    const float4* hv = (const float4*)(ahS + kc * 128);
    float s = 0.f;
#pragma unroll 8
    for (int i = 0; i < 32; i++) {
      float4 wq = wv[i], hh = hv[i];
      s += wq.x * hh.x + wq.y * hh.y + wq.z * hh.z + wq.w * hh.w;
    }
    pp[a][kc] = s;
  }
  __syncthreads();
  if (tid < 128) {
    float s = 0.f;
#pragma unroll
    for (int kc = 0; kc < 8; kc++) s += pp[tid][kc];
    pqS[tid] = s;
  }
  if (ti < T_INN) {
    // conv, k-outer: window element read ONCE (float2), 8 reg accumulators
    float sacc[8] = {0.f, 0.f, 0.f, 0.f, 0.f, 0.f, 0.f, 0.f};
#pragma unroll
    for (int k = 0; k < 31; k++) {
      int tt = ti + k - 15;
      if (tt >= 0 && tt < T_INN) {
        float2 v = acS[tt];
#pragma unroll
        for (int f8 = 0; f8 < 8; f8++) {
          int f = g * 8 + f8;
          sacc[f8] += Wconv[f * 62 + k] * v.x + Wconv[f * 62 + 31 + k] * v.y;
        }
      }
    }
#pragma unroll
    for (int f8 = 0; f8 < 8; f8++) convS[ti][g * 8 + f8] = sacc[f8];
  }
  __syncthreads();
  float e = 0.f;
  if (ti < T_INN) {
    // energies: convS row hoisted once (32 regs), then pure-VALU loop
    float cv[32];
#pragma unroll
    for (int f = 0; f < 32; f++) cv[f] = convS[ti][f];
    const float* pm = pmT + ((size_t)b * 128 + g * 32) * T_INN + ti;
#pragma unroll 4
    for (int aa = 0; aa < 32; aa++) {
      int a = g * 32 + aa;
      float x = pqS[a] + pm[(size_t)aa * T_INN];
      const float* wl = Wloc + a * 32;
#pragma unroll
      for (int f = 0; f < 32; f++) x += wl[f] * cv[f];
      float ex2 = __expf(2.f * x);
      e += vvec[a] * (1.f - 2.f * __builtin_amdgcn_rcpf(ex2 + 1.f));
    }
  }
  ep[g][ti] = e;
  __syncthreads();
  // combine + mask; shuffle softmax (2 barriers instead of 16)
  float ev = -3.0e38f;
  if (tid < 256) {
    if (tid < T_INN) {
      ev = ep[0][tid] + ep[1][tid] + ep[2][tid] + ep[3][tid];
      if (tid >= lens[b]) ev = -100000000.0f;
    }
  }
  float mloc = ev;
#pragma unroll
  for (int o = 32; o > 0; o >>= 1) mloc = fmaxf(mloc, __shfl_xor(mloc, o));
  if (tid < 256 && (tid & 63) == 0) red[tid >> 6] = mloc;
  __syncthreads();
  float mx = fmaxf(fmaxf(red[0], red[1]), fmaxf(red[2], red[3]));
  float ex = (tid < T_INN) ? __expf(ev - mx) : 0.f;
  float sloc = ex;
#pragma unroll
  for (int o = 32; o > 0; o >>= 1) sloc += __shfl_xor(sloc, o);
  if (tid < 256 && (tid & 63) == 0) red[4 + (tid >> 6)] = sloc;
  __syncthreads();
  float inv = 1.0f / ((red[4] + red[5]) + (red[6] + red[7]));
  if (tid < T_INN) {
    float a = ex * inv;
    awS[tid] = a;
    aw[b * T_INN + tid] = a;
    awcum[b * T_INN + tid] = acS[tid].y + a;
    alignsOut[((size_t)b * T_OUTT + t) * T_INN + tid] = a;
  }
  __syncthreads();
  {
    int e0 = tid & 511, half = tid >> 9;
    const float* ep2 = enc + ((size_t)b * T_INN + half * 100) * DENC + e0;
    float s = 0.f;
#pragma unroll 4
    for (int tt = 0; tt < 100; tt++) s += awS[half * 100 + tt] * ep2[(size_t)tt * DENC];
    cpart[tid] = s;
  }
  __syncthreads();
  if (tid < 512) {
    float v2 = cpart[tid] + cpart[512 + tid];
    actxW[b * DENC + tid] = v2;
    actx_bf[b * DENC + tid] = f2bf(v2);
  }
}

extern "C" void kernel_launch(void* const* d_in, const int* in_sizes, int n_in,
                              void* d_out, int out_size, void* d_ws, size_t ws_size,
                              hipStream_t stream)
{
  const float* enc    = (const float*)d_in[0];
  const float* dec    = (const float*)d_in[1];
  const int*   lens   = (const int*)d_in[2];
  const float* W_p1   = (const float*)d_in[3];
  const float* W_p2   = (const float*)d_in[4];
  const float* W_ih_a = (const float*)d_in[5];
  const float* W_hh_a = (const float*)d_in[6];
  const float* b_a    = (const float*)d_in[7];
  const float* Wq     = (const float*)d_in[8];
  const float* Wmem   = (const float*)d_in[9];
  const float* vvec   = (const float*)d_in[10];
  const float* Wconv  = (const float*)d_in[11];
  const float* Wloc   = (const float*)d_in[12];
  const float* W_ih_d = (const float*)d_in[13];
  const float* W_hh_d = (const float*)d_in[14];
  const float* b_d    = (const float*)d_in[15];
  const float* Wp     = (const float*)d_in[16];
  const float* bp     = (const float*)d_in[17];

  float* ws = (float*)d_ws;
  size_t off = 0;
  u16* xs_bf = (u16*)(ws + off); off += (size_t)T_OUTT * 64 * 256 / 2;
  float* pmT = ws + off; off += (size_t)64 * 128 * T_INN;
  u16* Wa_pack = (u16*)(ws + off); off += (size_t)4096 * 2048 / 2;   // KT=64 padded
  u16* Wd_pack = (u16*)(ws + off); off += (size_t)4096 * 2560 / 2;   // KT=80
  // state block (zero-initialized)
  float* stateBase = ws + off;
  float* ah    = stateBase;            // f32 [64][1024]
  float* dh    = ah + 65536;
  float* ac    = dh + 65536;
  float* dc    = ac + 65536;
  float* actx  = dc + 65536;           // [2][64][512] parity
  float* aw    = actx + 2 * 32768;
  float* awcum = aw + 12800;
  u16* ah_bf   = (u16*)(awcum + 12800);     // [2][64][1024]
  u16* dh_bf   = ah_bf + 2 * 65536;         // [2][64][1024]
  u16* actx_bf = dh_bf + 2 * 65536;         // [64][512]
  size_t stateFloats = 4 * 65536 + 2 * 32768 + 2 * 12800
                     + (2 * 65536 + 2 * 65536 + 32768) / 2;
  off += stateFloats;
  float* scratch = ws + off;           // precompute only
  float* h1 = scratch;                 // 399*64 x 256
  float* pmt = scratch;                // reused after prenet

  float* outsOut   = (float*)d_out;
  float* alignsOut = outsOut + (size_t)BB * T_OUTT * NMEL;

  // zero recurrent state + t=0 prenet row; zero Wa_pack (KT padding)
  hipMemsetAsync(stateBase, 0, stateFloats * sizeof(float), stream);
  hipMemsetAsync(xs_bf, 0, (size_t)64 * 256 * sizeof(u16), stream);
  hipMemsetAsync(Wa_pack, 0, (size_t)4096 * 2048 * sizeof(u16), stream);

  // ---- precompute ----
  {
    int tot;
    tot = 256 * 24 * 64;
    pack_w_kernel<<<(tot + 255) / 256, 256, 0, stream>>>(W_ih_a, Wa_pack, 768, 24, 0, 64, tot);
    tot = 256 * 32 * 64;
    pack_w_kernel<<<(tot + 255) / 256, 256, 0, stream>>>(W_hh_a, Wa_pack, 1024, 32, 24, 64, tot);
    tot = 256 * 48 * 64;
    pack_w_kernel<<<(tot + 255) / 256, 256, 0, stream>>>(W_ih_d, Wd_pack, 1536, 48, 0, 80, tot);
    tot = 256 * 32 * 64;
    pack_w_kernel<<<(tot + 255) / 256, 256, 0, stream>>>(W_hh_d, Wd_pack, 1024, 32, 48, 80, tot);
  }
  gemm_pre_kernel<<<dim3(4, 399), 256, 0, stream>>>(dec, 80, W_p1, 80, h1, nullptr, 256, 80, 1);
  gemm_pre_kernel<<<dim3(4, 399), 256, 0, stream>>>(h1, 256, W_p2, 256, nullptr, xs_bf + 64 * 256, 256, 256, 1);
  gemm_pre_kernel<<<dim3(2, 200), 256, 0, stream>>>(enc, 512, Wmem, 512, pmt, nullptr, 128, 512, 0);
  transpose_pm_kernel<<<dim3(7, 4, 64), dim3(32, 8), 0, stream>>>(pmt, pmT);

  // ---- decode loop: 2 dispatches per step ----
  for (int t = 0; t <= T_OUTT; t++) {
    int tc = (t < T_OUTT) ? t : 0;
    gates_kernel<<<dim3(64, 2, 2), 1024, 0, stream>>>(
        xs_bf + (size_t)tc * 64 * 256,
        actx_bf,
        ah_bf + (size_t)((t + 1) & 1) * 65536, ah_bf + (size_t)(t & 1) * 65536,
        dh_bf + (size_t)(t & 1) * 65536,       dh_bf + (size_t)((t + 1) & 1) * 65536,
        Wa_pack, Wd_pack, b_a, b_d, ah, ac, dh, dc, t);
    fused_step_kernel<<<128, 1024, 0, stream>>>(
        ah, dh, actx, actx_bf, aw, awcum, pmT, Wq, Wconv, Wloc, vvec,
        lens, enc, Wp, bp, outsOut, alignsOut, t);
  }
}